// Round 9
// baseline (146.035 us; speedup 1.0000x reference)
//
#include <hip/hip_runtime.h>
#include <hip/hip_bf16.h>
#include <stdint.h>

// x: [16,128,56,56] f32, w: [256,128,3,3] f32, bias: [256] f32
// out: [16,256,56,56] f32
// Implicit GEMM: M=Cout=256, N=pixels=50176, K = (kh*3+kw, c) = 1152
// Round 8b: occupancy push with the N64 invariant restored (R8's N128 tiles
// crossed image boundaries -> patch overflow -> NaN; 3136/64=49 so N64 never
// crosses). Block = M256 x N64, 512 thr = 8 waves (wave = M32 group).
// LDS = 48 KB patch -> 3 blocks/CU = 6 waves/SIMD (2x R7). Register
// pipelines unchanged: A dist-2 ring (L2->reg), B dist-1 dbuf (LDS->reg),
// barrier-free K-loop.

typedef __attribute__((ext_vector_type(8))) short short8;
typedef __attribute__((ext_vector_type(4))) float floatx4;

__device__ static inline void gload_lds16(const void* g, void* l) {
  typedef const __attribute__((address_space(1))) unsigned int* gp_t;
  typedef __attribute__((address_space(3))) unsigned int* lp_t;
  __builtin_amdgcn_global_load_lds((gp_t)(uintptr_t)g, (lp_t)(uint32_t)(uintptr_t)l,
                                   16, 0, 0);
}

// ---------- fused pre-pass: NCHW f32 -> padded NHWC bf16 (halo zeroed)
//   + weight f32 -> bf16 in MFMA-frag order wt2[g=m/16][kq][ch][ks][q][r][e]
//   byte strides: r=16, q=256, ks=1024, ch=2048, kq=4096, g=36864 ----------
__global__ __launch_bounds__(256)
void pre_kernel(const float* __restrict__ x, const float* __restrict__ wsrc,
                __hip_bfloat16* __restrict__ xp, __hip_bfloat16* __restrict__ wt) {
  const int b = blockIdx.x;
  if (b < 16 * 58) {
    const int n = b / 58, hp = b % 58;
    __hip_bfloat16* dst = xp + (size_t)(n * 58 + hp) * 58 * 128;
    if (hp == 0 || hp == 57) {
      const uint4 z = {0, 0, 0, 0};
      uint4* p = (uint4*)dst;
      for (int i = threadIdx.x; i < 928; i += 256) p[i] = z;
      return;
    }
    const int h = hp - 1;
    __shared__ float tile[128][57];
    const float* src = x + (size_t)n * (128 * 3136) + h * 56;
    for (int i = threadIdx.x; i < 128 * 14; i += 256) {
      const int c = i / 14, q = i - c * 14;
      const float4 v = ((const float4*)(src + (size_t)c * 3136))[q];
      tile[c][4 * q + 0] = v.x;
      tile[c][4 * q + 1] = v.y;
      tile[c][4 * q + 2] = v.z;
      tile[c][4 * q + 3] = v.w;
    }
    __syncthreads();
    if (threadIdx.x < 32) {
      const uint4 z = {0, 0, 0, 0};
      const int col = (threadIdx.x >> 4) * 57;
      ((uint4*)(dst + (size_t)col * 128))[threadIdx.x & 15] = z;
    }
    __hip_bfloat16* di = dst + 128;
    for (int i = threadIdx.x; i < 56 * 16; i += 256) {
      const int w = i >> 4, c8 = (i & 15) * 8;
      union { uint4 u; __hip_bfloat16 hh[8]; } pk;
#pragma unroll
      for (int j = 0; j < 8; ++j) pk.hh[j] = __float2bfloat16(tile[c8 + j][w]);
      *(uint4*)(di + (size_t)w * 128 + c8) = pk.u;
    }
  } else {
    const int base = (b - 928) * 256 + threadIdx.x;
    for (int t = base; t < 256 * 9 * 128; t += 36 * 256) {
      const int e = t & 7;
      const int rr = (t >> 3) & 15;
      const int q = (t >> 7) & 3;
      const int ks = (t >> 9) & 1;
      const int ch = (t >> 10) & 1;
      const int t11 = t >> 11;
      const int kq = t11 % 9;
      const int g = t11 / 9;
      const int cout = g * 16 + rr;
      const int c = ch * 64 + ks * 32 + q * 8 + e;
      wt[t] = __float2bfloat16(wsrc[(size_t)(cout * 128 + c) * 9 + kq]);
    }
  }
}

// ---------- main implicit-GEMM MFMA kernel ----------
// 512 thr = 8 waves, wave = M32 group (gbase = wave*2), all waves share N64.
// LDS: B-patch 192 rows x 256 B = 48 KB, staged once, read-only after barrier.
// Patch row = 16 x 16B chunks, chunk c at slot c ^ (row&7) (verified R1-R7).
__global__ __launch_bounds__(512, 6)
void conv_gemm_kernel(const __hip_bfloat16* __restrict__ xp,
                      const __hip_bfloat16* __restrict__ wt,
                      const float* __restrict__ bias,
                      float* __restrict__ out) {
  __shared__ __align__(16) char smem[49152];

  const int tid = threadIdx.x;
  const int lane = tid & 63;
  const int wave = tid >> 6;  // 0..7 -> M base wave*32
  const int col = lane & 15;
  const int quad = lane >> 4;

  // XCD-contiguous tiles: 784 = 8 XCD x 98 n-tiles (N64 each)
  const int id = blockIdx.x;
  const int xcd = id & 7;
  const int r = id >> 3;
  const int nt_ = xcd * 98 + r;
  const int n0 = nt_ * 64;  // 64 consecutive pixels; 3136/64=49 -> never crosses

  // patch base: padded-pixel index of pixel n0 at tap (0,0)
  const int nimg0 = n0 / 3136;
  const int rem0 = n0 - nimg0 * 3136;
  const int hh0 = rem0 / 56;
  const int ww0 = rem0 - hh0 * 56;
  const int P0 = (nimg0 * 58 + hh0) * 58 + ww0;
  const char* pbase = (const char*)xp + (size_t)P0 * 256;

  // ---- stage B-patch: 48 KB, 6 rounds x 512 thr x 16 B ----
#pragma unroll
  for (int i = 0; i < 6; ++i) {
    const int j = i * 512 + tid;
    const int row = j >> 4;    // 0..191
    const int slot = j & 15;
    gload_lds16(pbase + row * 256 + ((slot ^ (row & 7)) << 4),
                smem + i * 8192 + wave * 1024);
  }

  // ---- A-frag base pointers: wt2 + g*36864B + lane*16 ----
  const char* wtb = (const char*)wt;
  const char* pA0 = wtb + (size_t)(wave * 2) * 36864 + lane * 16;
  const char* pA1 = pA0 + 36864;
  // frag byte offset(kq,ch,ks) = kq*4096 + ch*2048 + ks*1024

  // ---- prefetch A for s=0 and s=1 (3-slot ring, distance 2) ----
  short8 areg[3][2][2];  // [ring slot][mt][ks]
#pragma unroll
  for (int s0 = 0; s0 < 2; ++s0) {
    const int ofs = (s0 & 1) * 2048;  // kq=0
#pragma unroll
    for (int ks = 0; ks < 2; ++ks) {
      areg[s0][0][ks] = *(const short8*)(pA0 + ofs + ks * 1024);
      areg[s0][1][ks] = *(const short8*)(pA1 + ofs + ks * 1024);
    }
  }

  // ---- per-lane patch row bases (tap (0,0)) ----
  int rbase[4];
#pragma unroll
  for (int nt = 0; nt < 4; ++nt) {
    const int pix = n0 + nt * 16 + col;
    const int ni = pix / 3136;
    const int re = pix - ni * 3136;
    const int ph = re / 56;
    const int pw = re - ph * 56;
    rbase[nt] = (ni * 58 + ph) * 58 + pw - P0;  // in [0, 67]
  }

  floatx4 acc[2][4];
#pragma unroll
  for (int a = 0; a < 2; ++a)
#pragma unroll
    for (int c = 0; c < 4; ++c) acc[a][c] = (floatx4)0.f;

  __syncthreads();  // patch ready (drains vmcnt; A(0..1) regs also arrive)

  // ---- preload B(0) from LDS into register buffer 0 ----
  short8 bfr[2][4][2];  // [buf][nt][ks]
#pragma unroll
  for (int nt = 0; nt < 4; ++nt) {
    const int rowB = rbase[nt];  // tap (0,0), ch=0
#pragma unroll
    for (int ks = 0; ks < 2; ++ks) {
      const int cB = ks * 4 + quad;
      const int pos = cB ^ (rowB & 7);
      bfr[0][nt][ks] = *(const short8*)(smem + rowB * 256 + (pos << 4));
    }
  }

  // ---- K loop: 18 steps, NO barriers; A at distance 2, B at distance 1 ----
#pragma unroll
  for (int s = 0; s < 18; ++s) {
    if (s < 16) {  // issue A(s+2) into ring slot (s+2)%3
      const int s2 = s + 2;
      const int ofs = (s2 >> 1) * 4096 + (s2 & 1) * 2048;
      const int slot = s2 % 3;
#pragma unroll
      for (int ks = 0; ks < 2; ++ks) {
        areg[slot][0][ks] = *(const short8*)(pA0 + ofs + ks * 1024);
        areg[slot][1][ks] = *(const short8*)(pA1 + ofs + ks * 1024);
      }
    }
    if (s < 17) {  // issue B(s+1) ds_reads into buffer (s+1)&1
      const int s1 = s + 1;
      const int kq1 = s1 >> 1, ch1 = s1 & 1;
      const int kh1 = kq1 / 3;
      const int tofs1 = kh1 * 58 + (kq1 - kh1 * 3);
      const int nb = s1 & 1;
#pragma unroll
      for (int nt = 0; nt < 4; ++nt) {
        const int rowB = rbase[nt] + tofs1;
#pragma unroll
        for (int ks = 0; ks < 2; ++ks) {
          const int cB = ch1 * 8 + ks * 4 + quad;
          const int pos = cB ^ (rowB & 7);
          bfr[nb][nt][ks] = *(const short8*)(smem + rowB * 256 + (pos << 4));
        }
      }
    }
    const int ca = s % 3, cb = s & 1;
#pragma unroll
    for (int ks = 0; ks < 2; ++ks)
#pragma unroll
      for (int mt = 0; mt < 2; ++mt)
#pragma unroll
        for (int nt = 0; nt < 4; ++nt)
          acc[mt][nt] = __builtin_amdgcn_mfma_f32_16x16x32_bf16(
              areg[ca][mt][ks], bfr[cb][nt][ks], acc[mt][nt], 0, 0, 0);
  }

  // ---- epilogue: bias + store (C/D: row m=quad*4+rr, col n=lane&15) ----
  const int rb = quad * 4;
#pragma unroll
  for (int nt = 0; nt < 4; ++nt) {
    const int pix = n0 + nt * 16 + col;
    const int nimg = pix / 3136;
    const int rem = pix - nimg * 3136;
    float* op = out + (size_t)nimg * (256 * 3136) + rem;
#pragma unroll
    for (int mt = 0; mt < 2; ++mt) {
      const int mb = wave * 32 + mt * 16 + rb;
#pragma unroll
      for (int rr = 0; rr < 4; ++rr) {
        op[(size_t)(mb + rr) * 3136] = acc[mt][nt][rr] + bias[mb + rr];
      }
    }
  }
}

// ---------- fallback: direct fp32 conv (only if ws too small) ----------
__global__ __launch_bounds__(256)
void direct_conv_kernel(const float* __restrict__ x, const float* __restrict__ wgt,
                        const float* __restrict__ bias, float* __restrict__ out) {
  const long t = (long)blockIdx.x * 256 + threadIdx.x;
  if (t >= 16L * 256 * 3136) return;
  const int w = t % 56;
  const int h = (t / 56) % 56;
  const int o = (t / 3136) % 256;
  const int n = t / (256L * 3136);
  float s = bias[o];
  for (int c = 0; c < 128; ++c)
    for (int kh = 0; kh < 3; ++kh) {
      const int hh = h + kh - 1;
      if (hh < 0 || hh >= 56) continue;
      for (int kw = 0; kw < 3; ++kw) {
        const int ww = w + kw - 1;
        if (ww < 0 || ww >= 56) continue;
        s += x[((size_t)(n * 128 + c) * 56 + hh) * 56 + ww] *
             wgt[((size_t)(o * 128 + c) * 3 + kh) * 3 + kw];
      }
    }
  out[t] = s;
}

extern "C" void kernel_launch(void* const* d_in, const int* in_sizes, int n_in,
                              void* d_out, int out_size, void* d_ws, size_t ws_size,
                              hipStream_t stream) {
  const float* x = (const float*)d_in[0];
  const float* w = (const float*)d_in[1];
  const float* b = (const float*)d_in[2];
  float* out = (float*)d_out;

  const size_t xp_bytes = (size_t)16 * 58 * 58 * 128 * 2;  // 13,778,944
  const size_t wt_bytes = (size_t)256 * 9 * 128 * 2;       //    589,824
  // NOTE: last blocks' patch staging reads up to ~2 KB past xp's end — lands in
  // wt region (still inside d_ws), values never used by compute. Safe.

  if (ws_size >= xp_bytes + wt_bytes) {
    __hip_bfloat16* xp = (__hip_bfloat16*)d_ws;
    __hip_bfloat16* wt = (__hip_bfloat16*)((char*)d_ws + xp_bytes);
    hipLaunchKernelGGL(pre_kernel, dim3(16 * 58 + 36), dim3(256), 0, stream,
                       x, w, xp, wt);
    hipLaunchKernelGGL(conv_gemm_kernel, dim3(784), dim3(512), 0, stream,
                       xp, wt, b, out);
  } else {
    const long total = 16L * 256 * 3136;
    hipLaunchKernelGGL(direct_conv_kernel, dim3((unsigned)((total + 255) / 256)),
                       dim3(256), 0, stream, x, w, b, out);
  }
}

// Round 10
// 128.777 us; speedup vs baseline: 1.1340x; 1.1340x over previous
//
#include <hip/hip_runtime.h>
#include <hip/hip_bf16.h>
#include <stdint.h>

// x: [16,128,56,56] f32, w: [256,128,3,3] f32, bias: [256] f32
// out: [16,256,56,56] f32
// Implicit GEMM: M=Cout=256, N=pixels=50176, K = (kh*3+kw, c) = 1152
// Round 10: M-fused block = M256 x N64, 4 waves, wave = M64 (4 m-groups).
// B-frag reuse per ds_read doubles (4 m-tiles), patch staged once per n-tile
// (halved staging), grid 784 = 3.06 blocks/CU. LDS 48 KB -> 3 blocks/CU,
// launch_bounds(256,3) caps VGPR at 170 (R9 lesson: compiler de-pipelines
// deep reg buffers; keep live set small instead). Barrier-free K-loop,
// A loads in-step from L2 (frag-ordered wt2), B ds_reads at use.

typedef __attribute__((ext_vector_type(8))) short short8;
typedef __attribute__((ext_vector_type(4))) float floatx4;

__device__ static inline void gload_lds16(const void* g, void* l) {
  typedef const __attribute__((address_space(1))) unsigned int* gp_t;
  typedef __attribute__((address_space(3))) unsigned int* lp_t;
  __builtin_amdgcn_global_load_lds((gp_t)(uintptr_t)g, (lp_t)(uint32_t)(uintptr_t)l,
                                   16, 0, 0);
}

// ---------- fused pre-pass: NCHW f32 -> padded NHWC bf16 (halo zeroed)
//   + weight f32 -> bf16 in MFMA-frag order wt2[g=m/16][kq][ch][ks][q][r][e]
//   byte strides: r=16, q=256, ks=1024, ch=2048, kq=4096, g=36864 ----------
__global__ __launch_bounds__(256)
void pre_kernel(const float* __restrict__ x, const float* __restrict__ wsrc,
                __hip_bfloat16* __restrict__ xp, __hip_bfloat16* __restrict__ wt) {
  const int b = blockIdx.x;
  if (b < 16 * 58) {
    const int n = b / 58, hp = b % 58;
    __hip_bfloat16* dst = xp + (size_t)(n * 58 + hp) * 58 * 128;
    if (hp == 0 || hp == 57) {
      const uint4 z = {0, 0, 0, 0};
      uint4* p = (uint4*)dst;
      for (int i = threadIdx.x; i < 928; i += 256) p[i] = z;
      return;
    }
    const int h = hp - 1;
    __shared__ float tile[128][57];
    const float* src = x + (size_t)n * (128 * 3136) + h * 56;
    for (int i = threadIdx.x; i < 128 * 14; i += 256) {
      const int c = i / 14, q = i - c * 14;
      const float4 v = ((const float4*)(src + (size_t)c * 3136))[q];
      tile[c][4 * q + 0] = v.x;
      tile[c][4 * q + 1] = v.y;
      tile[c][4 * q + 2] = v.z;
      tile[c][4 * q + 3] = v.w;
    }
    __syncthreads();
    if (threadIdx.x < 32) {
      const uint4 z = {0, 0, 0, 0};
      const int col = (threadIdx.x >> 4) * 57;
      ((uint4*)(dst + (size_t)col * 128))[threadIdx.x & 15] = z;
    }
    __hip_bfloat16* di = dst + 128;
    for (int i = threadIdx.x; i < 56 * 16; i += 256) {
      const int w = i >> 4, c8 = (i & 15) * 8;
      union { uint4 u; __hip_bfloat16 hh[8]; } pk;
#pragma unroll
      for (int j = 0; j < 8; ++j) pk.hh[j] = __float2bfloat16(tile[c8 + j][w]);
      *(uint4*)(di + (size_t)w * 128 + c8) = pk.u;
    }
  } else {
    const int base = (b - 928) * 256 + threadIdx.x;
    for (int t = base; t < 256 * 9 * 128; t += 36 * 256) {
      const int e = t & 7;
      const int rr = (t >> 3) & 15;
      const int q = (t >> 7) & 3;
      const int ks = (t >> 9) & 1;
      const int ch = (t >> 10) & 1;
      const int t11 = t >> 11;
      const int kq = t11 % 9;
      const int g = t11 / 9;
      const int cout = g * 16 + rr;
      const int c = ch * 64 + ks * 32 + q * 8 + e;
      wt[t] = __float2bfloat16(wsrc[(size_t)(cout * 128 + c) * 9 + kq]);
    }
  }
}

// ---------- main implicit-GEMM MFMA kernel ----------
// 256 thr = 4 waves; wave = M64 (m-groups wave*4 .. wave*4+3), all share N64.
// LDS: B-patch 192 rows x 256 B = 48 KB, staged once, read-only after barrier.
// Patch row = 16 x 16B chunks, chunk c at slot c ^ (row&7) (verified R1-R9).
__global__ __launch_bounds__(256, 3)
void conv_gemm_kernel(const __hip_bfloat16* __restrict__ xp,
                      const __hip_bfloat16* __restrict__ wt,
                      const float* __restrict__ bias,
                      float* __restrict__ out) {
  __shared__ __align__(16) char smem[49152];

  const int tid = threadIdx.x;
  const int lane = tid & 63;
  const int wave = tid >> 6;  // 0..3 -> Cout base wave*64
  const int col = lane & 15;
  const int quad = lane >> 4;

  // XCD-contiguous tiles: 784 = 8 XCD x 98 n-tiles (N64 each)
  const int id = blockIdx.x;
  const int xcd = id & 7;
  const int r = id >> 3;
  const int nt_ = xcd * 98 + r;
  const int n0 = nt_ * 64;  // 64 consecutive pixels; 3136/64=49 -> never crosses

  // patch base: padded-pixel index of pixel n0 at tap (0,0)
  const int nimg0 = n0 / 3136;
  const int rem0 = n0 - nimg0 * 3136;
  const int hh0 = rem0 / 56;
  const int ww0 = rem0 - hh0 * 56;
  const int P0 = (nimg0 * 58 + hh0) * 58 + ww0;
  const char* pbase = (const char*)xp + (size_t)P0 * 256;

  // ---- stage B-patch: 48 KB, 12 rounds x 256 thr x 16 B (once per n-tile) ----
#pragma unroll
  for (int i = 0; i < 12; ++i) {
    const int j = i * 256 + tid;
    const int row = j >> 4;    // 0..191
    const int slot = j & 15;
    gload_lds16(pbase + row * 256 + ((slot ^ (row & 7)) << 4),
                smem + i * 4096 + wave * 1024);
  }

  // ---- A-frag base pointers: wt2 + g*36864B + lane*16, g = wave*4 + mt ----
  const char* wtb = (const char*)wt;
  const char* pA = wtb + (size_t)(wave * 4) * 36864 + lane * 16;
  // frag byte offset(kq,ch,ks) = kq*4096 + ch*2048 + ks*1024; mt stride 36864

  // ---- per-lane patch row bases (tap (0,0)) ----
  int rbase[4];
#pragma unroll
  for (int nt = 0; nt < 4; ++nt) {
    const int pix = n0 + nt * 16 + col;
    const int ni = pix / 3136;
    const int re = pix - ni * 3136;
    const int ph = re / 56;
    const int pw = re - ph * 56;
    rbase[nt] = (ni * 58 + ph) * 58 + pw - P0;  // in [0, 67]
  }

  floatx4 acc[4][4];
#pragma unroll
  for (int a = 0; a < 4; ++a)
#pragma unroll
    for (int c = 0; c < 4; ++c) acc[a][c] = (floatx4)0.f;

  __syncthreads();  // patch ready (drains staging vmcnt)

  // ---- K loop: 18 steps, NO barriers; loads in-step, compiler-scheduled ----
#pragma unroll
  for (int s = 0; s < 18; ++s) {
    const int kq = s >> 1, ch = s & 1;
    const int kh = kq / 3;
    const int tofs = kh * 58 + (kq - kh * 3);
    const int aofs = kq * 4096 + ch * 2048;

    short8 af[4][2];  // [mt][ks] from L2 (frag-ordered wt2)
#pragma unroll
    for (int mt = 0; mt < 4; ++mt)
#pragma unroll
      for (int ks = 0; ks < 2; ++ks)
        af[mt][ks] = *(const short8*)(pA + mt * 36864 + aofs + ks * 1024);

    short8 bf[4][2];  // [nt][ks] from LDS patch
#pragma unroll
    for (int nt = 0; nt < 4; ++nt) {
      const int rowB = rbase[nt] + tofs;
#pragma unroll
      for (int ks = 0; ks < 2; ++ks) {
        const int cB = ch * 8 + ks * 4 + quad;
        const int pos = cB ^ (rowB & 7);
        bf[nt][ks] = *(const short8*)(smem + rowB * 256 + (pos << 4));
      }
    }

#pragma unroll
    for (int ks = 0; ks < 2; ++ks)
#pragma unroll
      for (int mt = 0; mt < 4; ++mt)
#pragma unroll
        for (int nt = 0; nt < 4; ++nt)
          acc[mt][nt] = __builtin_amdgcn_mfma_f32_16x16x32_bf16(
              af[mt][ks], bf[nt][ks], acc[mt][nt], 0, 0, 0);
  }

  // ---- epilogue: bias + store (C/D: row m=quad*4+rr, col n=lane&15) ----
  const int rb = quad * 4;
#pragma unroll
  for (int nt = 0; nt < 4; ++nt) {
    const int pix = n0 + nt * 16 + col;
    const int nimg = pix / 3136;
    const int rem = pix - nimg * 3136;
    float* op = out + (size_t)nimg * (256 * 3136) + rem;
#pragma unroll
    for (int mt = 0; mt < 4; ++mt) {
      const int mb = wave * 64 + mt * 16 + rb;
#pragma unroll
      for (int rr = 0; rr < 4; ++rr) {
        op[(size_t)(mb + rr) * 3136] = acc[mt][nt][rr] + bias[mb + rr];
      }
    }
  }
}

// ---------- fallback: direct fp32 conv (only if ws too small) ----------
__global__ __launch_bounds__(256)
void direct_conv_kernel(const float* __restrict__ x, const float* __restrict__ wgt,
                        const float* __restrict__ bias, float* __restrict__ out) {
  const long t = (long)blockIdx.x * 256 + threadIdx.x;
  if (t >= 16L * 256 * 3136) return;
  const int w = t % 56;
  const int h = (t / 56) % 56;
  const int o = (t / 3136) % 256;
  const int n = t / (256L * 3136);
  float s = bias[o];
  for (int c = 0; c < 128; ++c)
    for (int kh = 0; kh < 3; ++kh) {
      const int hh = h + kh - 1;
      if (hh < 0 || hh >= 56) continue;
      for (int kw = 0; kw < 3; ++kw) {
        const int ww = w + kw - 1;
        if (ww < 0 || ww >= 56) continue;
        s += x[((size_t)(n * 128 + c) * 56 + hh) * 56 + ww] *
             wgt[((size_t)(o * 128 + c) * 3 + kh) * 3 + kw];
      }
    }
  out[t] = s;
}

extern "C" void kernel_launch(void* const* d_in, const int* in_sizes, int n_in,
                              void* d_out, int out_size, void* d_ws, size_t ws_size,
                              hipStream_t stream) {
  const float* x = (const float*)d_in[0];
  const float* w = (const float*)d_in[1];
  const float* b = (const float*)d_in[2];
  float* out = (float*)d_out;

  const size_t xp_bytes = (size_t)16 * 58 * 58 * 128 * 2;  // 13,778,944
  const size_t wt_bytes = (size_t)256 * 9 * 128 * 2;       //    589,824
  // NOTE: last blocks' patch staging reads up to ~2 KB past xp's end — lands in
  // wt region (still inside d_ws), values never used by compute. Safe.

  if (ws_size >= xp_bytes + wt_bytes) {
    __hip_bfloat16* xp = (__hip_bfloat16*)d_ws;
    __hip_bfloat16* wt = (__hip_bfloat16*)((char*)d_ws + xp_bytes);
    hipLaunchKernelGGL(pre_kernel, dim3(16 * 58 + 36), dim3(256), 0, stream,
                       x, w, xp, wt);
    hipLaunchKernelGGL(conv_gemm_kernel, dim3(784), dim3(256), 0, stream,
                       xp, wt, b, out);
  } else {
    const long total = 16L * 256 * 3136;
    hipLaunchKernelGGL(direct_conv_kernel, dim3((unsigned)((total + 255) / 256)),
                       dim3(256), 0, stream, x, w, b, out);
  }
}